// Round 12
// baseline (280.784 us; speedup 1.0000x reference)
//
#include <hip/hip_runtime.h>
#include <cstdint>
#include <cstddef>

#define HH 128
#define SLOPE 0.01f

typedef __attribute__((ext_vector_type(8))) __bf16 bf16x8;
typedef __attribute__((ext_vector_type(8))) unsigned short ushort8v;
typedef __attribute__((ext_vector_type(4))) float f32x4;

__device__ __forceinline__ float lrelu(float x) { return x >= 0.f ? x : SLOPE * x; }
__device__ __forceinline__ unsigned short f2b(float f) {
  union { float f; unsigned u; } v; v.f = f;
  unsigned r = v.u + 0x7fffu + ((v.u >> 16) & 1u);  // round-to-nearest-even
  return (unsigned short)(r >> 16);
}
__device__ __forceinline__ float b2f(unsigned short u) {
  union { unsigned u; float f; } v; v.u = ((unsigned)u) << 16; return v.f;
}

// LDS tile layout with XOR swizzle: element (r,k) of a [rows]x128 bf16 tile lives at
// lofs(r,k). 16B chunks (8 ushorts) stay contiguous; chunk index ^= (r&15).
__device__ __forceinline__ int lofs(int r, int k) {
  return (r << 7) + ((((k >> 3) ^ r) & 15) << 3) + (k & 7);
}

// Single-wave LDS write->read sync: wave is lockstep (one PC); lgkmcnt(0) drain +
// compiler fence is sufficient for within-wave cross-lane exchange.
#define WAVE_SYNC() asm volatile("s_waitcnt lgkmcnt(0)" ::: "memory")

// Async global->LDS DMA, 16B per lane. LDS dest must be the WAVE-UNIFORM base;
// HW adds lane*16. Global src is per-lane. Drained by the vmcnt(0) the compiler
// emits before every s_barrier/__syncthreads.
__device__ __forceinline__ void gll16(const void* g, void* l) {
  __builtin_amdgcn_global_load_lds((const __attribute__((address_space(1))) void*)g,
                                   (__attribute__((address_space(3))) void*)l, 16, 0, 0);
}

// ---------------- CSR build (8-padded rows: agg has no tail code) ----------------

// count + rank: atomicAdd's return value is this edge's within-node rank.
__global__ __launch_bounds__(256) void count_kernel(const int* __restrict__ dst,
                                                    int* __restrict__ cnt,
                                                    int* __restrict__ rank, int nE) {
  int e = blockIdx.x * 256 + threadIdx.x;
  if (e < nE) rank[e] = atomicAdd(&cnt[dst[e]], 1);
}

// rowptr scans ceil8(deg) (padded); dinv uses the RAW degree.
__global__ __launch_bounds__(1024) void scan1_kernel(int* __restrict__ cnt,
                                                     int* __restrict__ rowptr,
                                                     int* __restrict__ bsum,
                                                     float* __restrict__ dinv, int n) {
  __shared__ int wsum[16];
  const int tid = threadIdx.x;
  const int lane = tid & 63, wid = tid >> 6;
  int i = blockIdx.x * 1024 + tid;
  int v = (i < n) ? cnt[i] : 0;
  int vp = (v + 7) & ~7;  // padded degree
  int x = vp;
#pragma unroll
  for (int off = 1; off < 64; off <<= 1) {
    int y = __shfl_up(x, off, 64);
    if (lane >= off) x += y;
  }
  if (lane == 63) wsum[wid] = x;
  __syncthreads();
  if (tid == 0) {
    int s = 0;
#pragma unroll
    for (int w = 0; w < 16; ++w) { int t = wsum[w]; wsum[w] = s; s += t; }
    bsum[blockIdx.x] = s;
  }
  __syncthreads();
  if (i < n) {
    rowptr[i] = wsum[wid] + x - vp;  // local exclusive (padded)
    dinv[i] = rsqrtf((float)v + 1.0f);
  }
}

// exclusive scan of block sums; rowptr[n] = total PADDED edge count.
__global__ __launch_bounds__(64) void scan2_kernel(int* __restrict__ bsum, int nb,
                                                   int* __restrict__ rowptr, int n) {
  int lane = threadIdx.x;
  int v = (lane < nb) ? bsum[lane] : 0;
  int x = v;
#pragma unroll
  for (int off = 1; off < 64; off <<= 1) {
    int y = __shfl_up(x, off, 64);
    if (lane >= off) x += y;
  }
  int tot = __shfl(x, nb - 1);
  if (lane < nb) bsum[lane] = x - v;  // exclusive
  if (lane == 0) rowptr[n] = tot;
}

__global__ __launch_bounds__(1024) void scan3_kernel(int* __restrict__ rowptr,
                                                     const int* __restrict__ bsum, int n) {
  int i = blockIdx.x * 1024 + threadIdx.x;
  if (i < n) rowptr[i] += bsum[blockIdx.x];
}

// csr entry: .x = src node, .y = norm (float bits). Atomic-free (rank-based).
// Padding slots (deg..ceil8) stay {0, 0.0f} from the csr memset -> fma no-ops.
__global__ __launch_bounds__(256) void fill_kernel(const int* __restrict__ src,
                                                   const int* __restrict__ dst,
                                                   const int* __restrict__ rowptr,
                                                   const int* __restrict__ rank,
                                                   const float* __restrict__ dinv,
                                                   int2* __restrict__ csr, int nE) {
  int e = blockIdx.x * 256 + threadIdx.x;
  if (e >= nE) return;
  int d = dst[e], s = src[e];
  int pos = rowptr[d] + rank[e];
  int2 ent;
  ent.x = s;
  ent.y = __float_as_int(dinv[s] * dinv[d]);
  csr[pos] = ent;
}

// ---------------- weight pack: B-fragment order for mfma 16x16x32 ----------------
__global__ __launch_bounds__(256) void pack_kernel(const float* W0, const float* W1,
                                                   const float* W2, const float* W3,
                                                   const float* W4, const float* W5,
                                                   unsigned short* __restrict__ out) {
  const float* Ws[6] = {W0, W1, W2, W3, W4, W5};
  const float* W = Ws[blockIdx.y];
  int f = blockIdx.x * 256 + threadIdx.x;  // 0..16383
  int j = f & 7, L = (f >> 3) & 63, c = (f >> 9) & 7, t = f >> 12;
  int k = t * 32 + (L >> 4) * 8 + j;
  int n = c * 16 + (L & 15);
  out[(size_t)blockIdx.y * 16384 + f] = f2b(W[k * HH + n]);
}

// ---------------- shared device helpers ----------------

// 16-row MFMA stage; B-fragments from the block-shared LDS weight copy.
// Fragment f at bytes [f*1024 + lane*16] -> ds_read_b128, conflict-free.
__device__ __forceinline__ void mfma_ldsW(const bf16x8 af[4],
                                          const unsigned short* __restrict__ Wl,
                                          int lane, f32x4 acc[8]) {
#pragma unroll
  for (int c = 0; c < 8; ++c) acc[c] = (f32x4){0.f, 0.f, 0.f, 0.f};
#pragma unroll
  for (int t = 0; t < 4; ++t) {
    bf16x8 wf[8];
#pragma unroll
    for (int c = 0; c < 8; ++c) wf[c] = *(const bf16x8*)&Wl[(t * 8 + c) * 512 + lane * 8];
#pragma unroll
    for (int c = 0; c < 8; ++c)
      acc[c] = __builtin_amdgcn_mfma_f32_16x16x32_bf16(af[t], wf[c], acc[c], 0, 0, 0);
  }
}

// A-fragments from a 16-row swizzled LDS tile (arow = lane&15).
__device__ __forceinline__ void lds_afrags16(const unsigned short* __restrict__ Tl,
                                             int m, int quad, bf16x8 af[4]) {
#pragma unroll
  for (int t = 0; t < 4; ++t)
    af[t] = *(const bf16x8*)&Tl[lofs(m, t * 32 + quad * 8)];
}

// ---------------- GEMM: A(fp32)[nrows,128] @ Wp -> bf16 out ----------------
// 4 waves/block, 16 rows/wave. Weights DMA'd once per block into 32KB LDS via
// global_load_lds (zero VGPR cost). r8-verified.

__global__ __launch_bounds__(256, 1) void gemm_conv(const float* __restrict__ A,
                                                    const unsigned short* __restrict__ Wp,
                                                    unsigned short* __restrict__ out, int nrows) {
  __shared__ __align__(16) unsigned short Wl[16384];
  const int tid = threadIdx.x;
  const int lane = tid & 63, wave = tid >> 6;
  const int row0 = blockIdx.x * 64 + wave * 16;
  const int m = lane & 15, quad = lane >> 4;

  // async weight stage: 8 x 16B per lane, linear layout
#pragma unroll
  for (int i = 0; i < 8; ++i)
    gll16((const uint4*)Wp + i * 256 + tid, (uint4*)Wl + i * 256 + wave * 64);

  // A fragments straight from global fp32, converted in-register (hides DMA)
  const int gr = row0 + m;
  const bool rok = gr < nrows;
  const float* Arow = A + (size_t)gr * HH;
  bf16x8 af[4];
#pragma unroll
  for (int t = 0; t < 4; ++t) {
    const int k = t * 32 + quad * 8;
    float4 lo = make_float4(0.f, 0.f, 0.f, 0.f), hi = lo;
    if (rok) {
      lo = *(const float4*)(Arow + k);
      hi = *(const float4*)(Arow + k + 4);
    }
    union { ushort8v u; bf16x8 b; } cv;
    cv.u[0] = f2b(lo.x); cv.u[1] = f2b(lo.y); cv.u[2] = f2b(lo.z); cv.u[3] = f2b(lo.w);
    cv.u[4] = f2b(hi.x); cv.u[5] = f2b(hi.y); cv.u[6] = f2b(hi.z); cv.u[7] = f2b(hi.w);
    af[t] = cv.b;
  }

  __syncthreads();  // drains vmcnt (DMA done) -> weights visible to all waves

  f32x4 acc[8];
  mfma_ldsW(af, Wl, lane, acc);

#pragma unroll
  for (int c = 0; c < 8; ++c) {
    int col = c * 16 + m;
#pragma unroll
    for (int g = 0; g < 4; ++g) {
      int row = row0 + quad * 4 + g;
      if (row < nrows) out[(size_t)row * HH + col] = f2b(acc[c][g]);
    }
  }
}

// ---------------- agg: one wave per node, tail-free (8-padded CSR) ----------------
// r11-verified structure (half-wave edge parity, ushort4 gathers, hoisted epilogue).

template <int RES, int OUTBF>
__global__ __launch_bounds__(256) void agg_kernel(const unsigned short* __restrict__ h,
                                                  const int* __restrict__ rowptr,
                                                  const int2* __restrict__ csr,
                                                  const float* __restrict__ dinv,
                                                  const float* __restrict__ bias,
                                                  const float* __restrict__ res,
                                                  void* __restrict__ outv, int n) {
  int node = blockIdx.x * 4 + (threadIdx.x >> 6);
  if (node >= n) return;
  const int lane = threadIdx.x & 63;
  const int p = lane >> 5;          // edge parity this half-wave handles
  const int c4 = (lane & 31) << 2;  // 4 columns per lane
  int j = rowptr[node];
  const int end = rowptr[node + 1];

  // hoisted epilogue inputs (independent of the gather loop)
  const float di = dinv[node];
  const ushort4 hs = *(const ushort4*)(h + (size_t)node * HH + c4);
  const float4 b = *(const float4*)(bias + c4);
  float4 rr = make_float4(0.f, 0.f, 0.f, 0.f);
  if (RES) rr = *(const float4*)(res + (size_t)node * HH + c4);

  float a0 = 0.f, a1 = 0.f, a2 = 0.f, a3 = 0.f;
  // 8 edges per iteration (4 per half-wave), 4 ushort4 gathers in flight/lane
  for (; j < end; j += 8) {
    int2 e[4];
    ushort4 r[4];
#pragma unroll
    for (int q = 0; q < 4; ++q) e[q] = csr[j + 2 * q + p];
#pragma unroll
    for (int q = 0; q < 4; ++q) r[q] = *(const ushort4*)(h + (size_t)e[q].x * HH + c4);
#pragma unroll
    for (int q = 0; q < 4; ++q) {
      float nv = __int_as_float(e[q].y);
      a0 = fmaf(b2f(r[q].x), nv, a0); a1 = fmaf(b2f(r[q].y), nv, a1);
      a2 = fmaf(b2f(r[q].z), nv, a2); a3 = fmaf(b2f(r[q].w), nv, a3);
    }
  }

  // combine the two edge-parity halves (lane L <-> lane L^32, same columns)
  a0 += __shfl_xor(a0, 32);
  a1 += __shfl_xor(a1, 32);
  a2 += __shfl_xor(a2, 32);
  a3 += __shfl_xor(a3, 32);

  if (p == 0) {  // lanes 0-31: epilogue + store (16B accesses)
    const float d2 = di * di;
    float o0 = a0 + b2f(hs.x) * d2 + b.x + rr.x;
    float o1 = a1 + b2f(hs.y) * d2 + b.y + rr.y;
    float o2 = a2 + b2f(hs.z) * d2 + b.z + rr.z;
    float o3 = a3 + b2f(hs.w) * d2 + b.w + rr.w;
    o0 = lrelu(o0); o1 = lrelu(o1); o2 = lrelu(o2); o3 = lrelu(o3);
    if (OUTBF) {
      ushort4 o;
      o.x = f2b(o0); o.y = f2b(o1); o.z = f2b(o2); o.w = f2b(o3);
      *(ushort4*)((unsigned short*)outv + (size_t)node * HH + c4) = o;
    } else {
      *(float4*)((float*)outv + (size_t)node * HH + c4) = make_float4(o0, o1, o2, o3);
    }
  }
}

// ---------------- fusedMLP: 4-GEMM chain, double-buffered W, 4 barriers --------
// Pipeline redesign (r12): Wl[2] ping-pong (64KB). W1+W2 DMA'd in the prologue;
// W3 issued at B2 (covered by stage 2), W4 at B3 (covered by stage 3) -> no
// refill DMA is ever exposed; barriers 7 -> 4. To keep 2 blocks/CU at 80KB LDS,
// each wave has ONE tile T (f2 -> m -> gen -> p -> q): f2 residual captured to
// 16 regs (stage 1), gen parked into T between its m-read and p-write, biases
// in 32 regs. VGPR ~150-190 (no cap at (256,1)) -> no spill expected.
// stage 1:  m  = leaky(f2@Wm1+bm1)                      T(f2) -> T(m)
// stage 2:  h3 = leaky(m@Wm2+bm2+f2res); p=0.5(h3+gen)  T(m,gen) -> T(p)
// stage 3:  q  = leaky(p@Wp1+bp1)                       T(p) -> T(q)
// stage 4:  out= leaky(q@Wp2+bp2)                       T(q) -> fp32 global

__global__ __launch_bounds__(256, 1) void fusedMLP(const unsigned short* __restrict__ f2bf,
                                                   const unsigned short* __restrict__ Wm1p,
                                                   const unsigned short* __restrict__ Wm2p,
                                                   const unsigned short* __restrict__ Wp1p,
                                                   const unsigned short* __restrict__ Wp2p,
                                                   const float* __restrict__ bm1,
                                                   const float* __restrict__ bm2,
                                                   const float* __restrict__ bp1,
                                                   const float* __restrict__ bp2,
                                                   const float* __restrict__ gen,
                                                   float* __restrict__ out, int n) {
  __shared__ __align__(16) unsigned short Wl[2][16384];   // 64KB weight ping-pong
  __shared__ __align__(16) unsigned short Tl[4][16 * HH]; // 16KB: one 4KB tile/wave
  const int tid = threadIdx.x;
  const int lane = tid & 63, wave = tid >> 6;
  const int row0 = blockIdx.x * 64 + wave * 16;
  const int m = lane & 15, quad = lane >> 4;
  unsigned short* T = Tl[wave];

  // --- issue W1 -> Wl[0] and W2 -> Wl[1] DMAs first (async) ---
#pragma unroll
  for (int i = 0; i < 8; ++i) {
    gll16((const uint4*)Wm1p + i * 256 + tid, (uint4*)Wl[0] + i * 256 + wave * 64);
    gll16((const uint4*)Wm2p + i * 256 + tid, (uint4*)Wl[1] + i * 256 + wave * 64);
  }

  // --- f2 tile -> T (swizzled), 4 x 16B per lane ---
#pragma unroll
  for (int i = 0; i < 4; ++i) {
    int idx = i * 64 + lane;            // 16B-chunk id 0..255
    int r = idx >> 4, k = (idx & 15) << 3;
    int gr = row0 + r;
    ushort8v v = {0, 0, 0, 0, 0, 0, 0, 0};
    if (gr < n) v = *(const ushort8v*)(f2bf + (size_t)gr * HH + k);
    *(ushort8v*)&T[lofs(r, k)] = v;
  }

  // --- gen -> bf16 regs in staging-chunk layout (parked into T at stage 2) ---
  ushort4 genb[8];
#pragma unroll
  for (int i = 0; i < 8; ++i) {
    int idx = i * 64 + lane;            // float4-chunk id 0..511
    int r = idx >> 5, c4 = (idx & 31) << 2;
    int gr = row0 + r;
    float4 v = make_float4(0.f, 0.f, 0.f, 0.f);
    if (gr < n) v = *(const float4*)(gen + (size_t)gr * HH + c4);
    genb[i].x = f2b(v.x); genb[i].y = f2b(v.y); genb[i].z = f2b(v.z); genb[i].w = f2b(v.w);
  }

  // --- all 4 bias sets -> registers (32 x 4B loads, hidden under DMAs) ---
  float bvAll[4][8];
#pragma unroll
  for (int cc = 0; cc < 8; ++cc) {
    int col = cc * 16 + m;
    bvAll[0][cc] = bm1[col];
    bvAll[1][cc] = bm2[col];
    bvAll[2][cc] = bp1[col];
    bvAll[3][cc] = bp2[col];
  }

  __syncthreads();  // B1: vmcnt drain -> W1, W2, T visible

  bf16x8 af[4];
  f32x4 acc[8];

  // ---- stage 1: m = leaky(f2@Wm1+bm1) ----
  lds_afrags16(T, m, quad, af);
  // capture f2 residual (C-fragment slots) into 16 regs before T is overwritten
  unsigned f2res[8][2];
#pragma unroll
  for (int cc = 0; cc < 8; ++cc) {
    int col = cc * 16 + m;
#pragma unroll
    for (int gp = 0; gp < 2; ++gp) {
      int lr = quad * 4 + gp * 2;
      f2res[cc][gp] = (unsigned)T[lofs(lr, col)] | ((unsigned)T[lofs(lr + 1, col)] << 16);
    }
  }
  mfma_ldsW(af, Wl[0], lane, acc);
  WAVE_SYNC();  // all T reads drained before overwrite
#pragma unroll
  for (int cc = 0; cc < 8; ++cc) {
    int col = cc * 16 + m;
#pragma unroll
    for (int g = 0; g < 4; ++g)
      T[lofs(quad * 4 + g, col)] = f2b(lrelu(acc[cc][g] + bvAll[0][cc]));
  }
  __syncthreads();  // B2: all waves done reading W1 (Wl[0] free); T(m) visible

  // issue W3 -> Wl[0] (covered by all of stage 2)
#pragma unroll
  for (int i = 0; i < 8; ++i)
    gll16((const uint4*)Wp1p + i * 256 + tid, (uint4*)Wl[0] + i * 256 + wave * 64);

  // ---- stage 2: h3 = leaky(m@Wm2+bm2+f2res); p = 0.5*(h3+gen) ----
  lds_afrags16(T, m, quad, af);  // consume m into regs
  WAVE_SYNC();                   // m reads done before gen park overwrites T
  // park gen into T (staging layout)
#pragma unroll
  for (int i = 0; i < 8; ++i) {
    int idx = i * 64 + lane;
    int r = idx >> 5, c4 = (idx & 31) << 2;
    *(ushort4*)&T[lofs(r, c4)] = genb[i];
  }
  mfma_ldsW(af, Wl[1], lane, acc);  // W2 resident since B1 — no barrier needed
  WAVE_SYNC();                      // gen park visible for C-slot reads
#pragma unroll
  for (int cc = 0; cc < 8; ++cc) {
    int col = cc * 16 + m;
#pragma unroll
    for (int g = 0; g < 4; ++g) {
      int lr = quad * 4 + g;
      unsigned fr = f2res[cc][g >> 1];
      float f2v = b2f((unsigned short)((g & 1) ? (fr >> 16) : (fr & 0xffffu)));
      float v = lrelu(acc[cc][g] + bvAll[1][cc] + f2v);
      float gv = b2f(T[lofs(lr, col)]);     // gen parked (same-lane slot)
      T[lofs(lr, col)] = f2b(0.5f * (v + gv));
    }
  }
  __syncthreads();  // B3: all waves done reading W2 (Wl[1] free); W3 visible

  // issue W4 -> Wl[1] (covered by all of stage 3)
#pragma unroll
  for (int i = 0; i < 8; ++i)
    gll16((const uint4*)Wp2p + i * 256 + tid, (uint4*)Wl[1] + i * 256 + wave * 64);

  // ---- stage 3: q = leaky(p@Wp1+bp1) ----
  lds_afrags16(T, m, quad, af);
  mfma_ldsW(af, Wl[0], lane, acc);
  WAVE_SYNC();  // p reads drained before overwrite
#pragma unroll
  for (int cc = 0; cc < 8; ++cc) {
    int col = cc * 16 + m;
#pragma unroll
    for (int g = 0; g < 4; ++g)
      T[lofs(quad * 4 + g, col)] = f2b(lrelu(acc[cc][g] + bvAll[2][cc]));
  }
  __syncthreads();  // B4: W4 visible; T(q) visible

  // ---- stage 4: out = leaky(q@Wp2+bp2) ----
  lds_afrags16(T, m, quad, af);
  mfma_ldsW(af, Wl[1], lane, acc);
#pragma unroll
  for (int cc = 0; cc < 8; ++cc) {
    int col = cc * 16 + m;
#pragma unroll
    for (int g = 0; g < 4; ++g) {
      int row = row0 + quad * 4 + g;
      if (row < n) out[(size_t)row * HH + col] = lrelu(acc[cc][g] + bvAll[3][cc]);
    }
  }
}

// ---------------- launcher ----------------

extern "C" void kernel_launch(void* const* d_in, const int* in_sizes, int n_in,
                              void* d_out, int out_size, void* d_ws, size_t ws_size,
                              hipStream_t stream) {
  const float* x   = (const float*)d_in[0];
  const int* ei    = (const int*)d_in[1];
  const float* gen = (const float*)d_in[2];
  const float* Wc1 = (const float*)d_in[3];
  const float* bc1 = (const float*)d_in[4];
  const float* Wc2 = (const float*)d_in[5];
  const float* bc2 = (const float*)d_in[6];
  const float* Wm1 = (const float*)d_in[7];
  const float* bm1 = (const float*)d_in[8];
  const float* Wm2 = (const float*)d_in[9];
  const float* bm2 = (const float*)d_in[10];
  const float* Wp1 = (const float*)d_in[11];
  const float* bp1 = (const float*)d_in[12];
  const float* Wp2 = (const float*)d_in[13];
  const float* bp2 = (const float*)d_in[14];

  const int N = in_sizes[0] / HH;
  const int E = in_sizes[1] / 2;
  const int* src = ei;
  const int* dst = ei + E;

  const size_t Epad = (size_t)E + 8 * (size_t)N;  // worst-case padded edge count

  char* ws = (char*)d_ws;
  size_t off = 0;
  auto alloc = [&](size_t bytes) { void* p = ws + off; off += (bytes + 255) & ~(size_t)255; return p; };
  float* dinv            = (float*)alloc((size_t)N * 4);
  int*   rowptr          = (int*)  alloc((size_t)(N + 1) * 4);
  int*   cnt             = (int*)  alloc((size_t)N * 4);
  int*   bsum            = (int*)  alloc((size_t)64 * 4);
  int*   rank            = (int*)  alloc((size_t)E * 4);
  int2*  csr             = (int2*) alloc(Epad * 8);
  unsigned short* h_bf   = (unsigned short*)alloc((size_t)N * HH * 2);
  unsigned short* t2_bf  = (unsigned short*)alloc((size_t)N * HH * 2);
  unsigned short* f2_bf  = (unsigned short*)alloc((size_t)N * HH * 2);
  float* f1_f32          = (float*)alloc((size_t)N * HH * 4);
  unsigned short* packed = (unsigned short*)alloc((size_t)6 * 16384 * 2);
  float* fOut = (float*)d_out;

  const int cblocks = (N + 63) / 64;      // 4 waves x 16 rows per 256-thr block
  const int eblocks = (E + 255) / 256;
  const int ablocks = (N + 3) / 4;
  const int sblocks = (N + 1023) / 1024;  // <= 64 for N <= 65536

  // weight packing
  pack_kernel<<<dim3(64, 6), 256, 0, stream>>>(Wc1, Wc2, Wm1, Wm2, Wp1, Wp2, packed);

  // CSR build (8-padded rows; fill is atomic-free; padding slots = {0, 0.0f})
  hipMemsetAsync(cnt, 0, (size_t)N * 4, stream);
  hipMemsetAsync(csr, 0, Epad * 8, stream);
  count_kernel<<<eblocks, 256, 0, stream>>>(dst, cnt, rank, E);
  scan1_kernel<<<sblocks, 1024, 0, stream>>>(cnt, rowptr, bsum, dinv, N);
  scan2_kernel<<<1, 64, 0, stream>>>(bsum, sblocks, rowptr, N);
  scan3_kernel<<<sblocks, 1024, 0, stream>>>(rowptr, bsum, N);
  fill_kernel<<<eblocks, 256, 0, stream>>>(src, dst, rowptr, rank, dinv, csr, E);

  // conv1: h_bf = bf16(x @ Wc1)
  gemm_conv<<<cblocks, 256, 0, stream>>>(x, packed + 0 * 16384, h_bf, N);
  // agg1: f1 = leaky(agg(h_bf)+self+bc1)  [fp32]
  agg_kernel<0, 0><<<ablocks, 256, 0, stream>>>(h_bf, rowptr, csr, dinv, bc1, nullptr, f1_f32, N);
  // conv2: t2 = bf16(f1 @ Wc2)
  gemm_conv<<<cblocks, 256, 0, stream>>>(f1_f32, packed + 1 * 16384, t2_bf, N);
  // agg2: f2 = leaky(agg(t2)+self+bc2+f1)  [bf16 — only consumed as bf16]
  agg_kernel<1, 1><<<ablocks, 256, 0, stream>>>(t2_bf, rowptr, csr, dinv, bc2, f1_f32, f2_bf, N);
  // fusedMLP: MLP + interp + proj -> d_out
  fusedMLP<<<cblocks, 256, 0, stream>>>(f2_bf,
                                        packed + 2 * 16384, packed + 3 * 16384,
                                        packed + 4 * 16384, packed + 5 * 16384,
                                        bm1, bm2, bp1, bp2, gen, fOut, N);
}

// Round 13
// 263.224 us; speedup vs baseline: 1.0667x; 1.0667x over previous
//
#include <hip/hip_runtime.h>
#include <cstdint>
#include <cstddef>

#define HH 128
#define SLOPE 0.01f

typedef __attribute__((ext_vector_type(8))) __bf16 bf16x8;
typedef __attribute__((ext_vector_type(8))) unsigned short ushort8v;
typedef __attribute__((ext_vector_type(4))) float f32x4;

__device__ __forceinline__ float lrelu(float x) { return x >= 0.f ? x : SLOPE * x; }
__device__ __forceinline__ unsigned short f2b(float f) {
  union { float f; unsigned u; } v; v.f = f;
  unsigned r = v.u + 0x7fffu + ((v.u >> 16) & 1u);  // round-to-nearest-even
  return (unsigned short)(r >> 16);
}
__device__ __forceinline__ float b2f(unsigned short u) {
  union { unsigned u; float f; } v; v.u = ((unsigned)u) << 16; return v.f;
}

// LDS tile layout with XOR swizzle: element (r,k) of a [rows]x128 bf16 tile lives at
// lofs(r,k). 16B chunks (8 ushorts) stay contiguous; chunk index ^= (r&15).
__device__ __forceinline__ int lofs(int r, int k) {
  return (r << 7) + ((((k >> 3) ^ r) & 15) << 3) + (k & 7);
}

// Single-wave LDS write->read sync: wave is lockstep (one PC); lgkmcnt(0) drain +
// compiler fence is sufficient for within-wave cross-lane exchange.
#define WAVE_SYNC() asm volatile("s_waitcnt lgkmcnt(0)" ::: "memory")

// Async global->LDS DMA, 16B per lane. LDS dest must be the WAVE-UNIFORM base;
// HW adds lane*16. Global src is per-lane. Drained by the vmcnt(0) the compiler
// emits before every s_barrier/__syncthreads.
__device__ __forceinline__ void gll16(const void* g, void* l) {
  __builtin_amdgcn_global_load_lds((const __attribute__((address_space(1))) void*)g,
                                   (__attribute__((address_space(3))) void*)l, 16, 0, 0);
}

// ---------------- K1: pack (384 blocks) || count (eblocks) ----------------
// Independent stages co-scheduled in one dispatch (blockIdx-partitioned).
// pack: B-fragment order for mfma 16x16x32. count: rank[e] = within-node rank.

__global__ __launch_bounds__(256) void k_pack_count(const float* W0, const float* W1,
                                                    const float* W2, const float* W3,
                                                    const float* W4, const float* W5,
                                                    unsigned short* __restrict__ outp,
                                                    const int* __restrict__ dst,
                                                    int* __restrict__ cnt,
                                                    int* __restrict__ rank, int nE) {
  const int bb = blockIdx.x;
  const int tid = threadIdx.x;
  if (bb < 384) {  // ---- pack path ----
    const float* Ws[6] = {W0, W1, W2, W3, W4, W5};
    const int mat = bb >> 6;
    const float* W = Ws[mat];
    int f = (bb & 63) * 256 + tid;  // 0..16383
    int j = f & 7, L = (f >> 3) & 63, c = (f >> 9) & 7, t = f >> 12;
    int k = t * 32 + (L >> 4) * 8 + j;
    int n = c * 16 + (L & 15);
    outp[(size_t)mat * 16384 + f] = f2b(W[k * HH + n]);
  } else {         // ---- count path ----
    int e = (bb - 384) * 256 + tid;
    if (e < nE) rank[e] = atomicAdd(&cnt[dst[e]], 1);
  }
}

// ---------------- CSR scans (8-padded rows) ----------------

// rowptr scans ceil8(deg) (padded); dinv uses the RAW degree. bsum = raw block sums.
__global__ __launch_bounds__(1024) void scan1_kernel(int* __restrict__ cnt,
                                                     int* __restrict__ rowptr,
                                                     int* __restrict__ bsum,
                                                     float* __restrict__ dinv, int n) {
  __shared__ int wsum[16];
  const int tid = threadIdx.x;
  const int lane = tid & 63, wid = tid >> 6;
  int i = blockIdx.x * 1024 + tid;
  int v = (i < n) ? cnt[i] : 0;
  int vp = (v + 7) & ~7;  // padded degree
  int x = vp;
#pragma unroll
  for (int off = 1; off < 64; off <<= 1) {
    int y = __shfl_up(x, off, 64);
    if (lane >= off) x += y;
  }
  if (lane == 63) wsum[wid] = x;
  __syncthreads();
  if (tid == 0) {
    int s = 0;
#pragma unroll
    for (int w = 0; w < 16; ++w) { int t = wsum[w]; wsum[w] = s; s += t; }
    bsum[blockIdx.x] = s;
  }
  __syncthreads();
  if (i < n) {
    rowptr[i] = wsum[wid] + x - vp;  // local exclusive (padded)
    dinv[i] = rsqrtf((float)v + 1.0f);
  }
}

// scan3 with inline bsum-scan (replaces scan2): nb <= 64 fits one wave.
// Each block computes the exclusive prefix of bsum for ITS blockIdx; block 0
// also writes rowptr[n] = total padded edge count.
__global__ __launch_bounds__(1024) void scan3_kernel(int* __restrict__ rowptr,
                                                     const int* __restrict__ bsum,
                                                     int n, int nb) {
  __shared__ int spfx, stot;
  const int tid = threadIdx.x;
  if (tid < 64) {
    int v = (tid < nb) ? bsum[tid] : 0;
    int x = v;
#pragma unroll
    for (int off = 1; off < 64; off <<= 1) {
      int y = __shfl_up(x, off, 64);
      if (tid >= off) x += y;
    }
    if (tid == (int)blockIdx.x) spfx = x - v;  // exclusive prefix for this block
    if (tid == nb - 1) stot = x;               // grand total (padded)
  }
  __syncthreads();
  int i = blockIdx.x * 1024 + tid;
  if (i < n) rowptr[i] += spfx;
  if (blockIdx.x == 0 && tid == 0) rowptr[n] = stot;
}

// ---------------- shared device helpers ----------------

// 16-row MFMA stage; B-fragments from the block-shared LDS weight copy.
// Fragment f at bytes [f*1024 + lane*16] -> ds_read_b128, conflict-free.
__device__ __forceinline__ void mfma_ldsW(const bf16x8 af[4],
                                          const unsigned short* __restrict__ Wl,
                                          int lane, f32x4 acc[8]) {
#pragma unroll
  for (int c = 0; c < 8; ++c) acc[c] = (f32x4){0.f, 0.f, 0.f, 0.f};
#pragma unroll
  for (int t = 0; t < 4; ++t) {
    bf16x8 wf[8];
#pragma unroll
    for (int c = 0; c < 8; ++c) wf[c] = *(const bf16x8*)&Wl[(t * 8 + c) * 512 + lane * 8];
#pragma unroll
    for (int c = 0; c < 8; ++c)
      acc[c] = __builtin_amdgcn_mfma_f32_16x16x32_bf16(af[t], wf[c], acc[c], 0, 0, 0);
  }
}

// A-fragments from a 16-row swizzled LDS tile (arow = lane&15).
__device__ __forceinline__ void lds_afrags16(const unsigned short* __restrict__ Tl,
                                             int m, int quad, bf16x8 af[4]) {
#pragma unroll
  for (int t = 0; t < 4; ++t)
    af[t] = *(const bf16x8*)&Tl[lofs(m, t * 32 + quad * 8)];
}

// gemm body (r8-verified): 4 waves/block, 16 rows/wave, weights DMA'd to 32KB LDS.
__device__ __forceinline__ void gemm_body(unsigned short* Wl,
                                          const float* __restrict__ A,
                                          const unsigned short* __restrict__ Wp,
                                          unsigned short* __restrict__ out,
                                          int nrows, int vb) {
  const int tid = threadIdx.x;
  const int lane = tid & 63, wave = tid >> 6;
  const int row0 = vb * 64 + wave * 16;
  const int m = lane & 15, quad = lane >> 4;

#pragma unroll
  for (int i = 0; i < 8; ++i)
    gll16((const uint4*)Wp + i * 256 + tid, (uint4*)Wl + i * 256 + wave * 64);

  const int gr = row0 + m;
  const bool rok = gr < nrows;
  const float* Arow = A + (size_t)gr * HH;
  bf16x8 af[4];
#pragma unroll
  for (int t = 0; t < 4; ++t) {
    const int k = t * 32 + quad * 8;
    float4 lo = make_float4(0.f, 0.f, 0.f, 0.f), hi = lo;
    if (rok) {
      lo = *(const float4*)(Arow + k);
      hi = *(const float4*)(Arow + k + 4);
    }
    union { ushort8v u; bf16x8 b; } cv;
    cv.u[0] = f2b(lo.x); cv.u[1] = f2b(lo.y); cv.u[2] = f2b(lo.z); cv.u[3] = f2b(lo.w);
    cv.u[4] = f2b(hi.x); cv.u[5] = f2b(hi.y); cv.u[6] = f2b(hi.z); cv.u[7] = f2b(hi.w);
    af[t] = cv.b;
  }

  __syncthreads();  // drains vmcnt (DMA done) -> weights visible

  f32x4 acc[8];
  mfma_ldsW(af, Wl, lane, acc);

#pragma unroll
  for (int c = 0; c < 8; ++c) {
    int col = c * 16 + m;
#pragma unroll
    for (int g = 0; g < 4; ++g) {
      int row = row0 + quad * 4 + g;
      if (row < nrows) out[(size_t)row * HH + col] = f2b(acc[c][g]);
    }
  }
}

// ---------------- K2: gemm1 (cblocks) || fill (eblocks) ----------------
// fill: csr entry .x = src, .y = norm bits; atomic-free (rank-based). Padding
// slots stay {0, 0.0f} from the memset -> fma no-ops in agg.

__global__ __launch_bounds__(256, 1) void k_gemm_fill(const float* __restrict__ A,
                                                      const unsigned short* __restrict__ Wp,
                                                      unsigned short* __restrict__ out, int nrows,
                                                      int gemmBlocks,
                                                      const int* __restrict__ src,
                                                      const int* __restrict__ dst,
                                                      const int* __restrict__ rowptr,
                                                      const int* __restrict__ rank,
                                                      const float* __restrict__ dinv,
                                                      int2* __restrict__ csr, int nE) {
  __shared__ __align__(16) unsigned short Wl[16384];
  const int bb = blockIdx.x;
  if (bb < gemmBlocks) {
    gemm_body(Wl, A, Wp, out, nrows, bb);
  } else {
    int e = (bb - gemmBlocks) * 256 + threadIdx.x;
    if (e >= nE) return;
    int d = dst[e], s = src[e];
    int pos = rowptr[d] + rank[e];
    int2 ent;
    ent.x = s;
    ent.y = __float_as_int(dinv[s] * dinv[d]);
    csr[pos] = ent;
  }
}

// plain gemm (conv2) — r8-verified
__global__ __launch_bounds__(256, 1) void gemm_conv(const float* __restrict__ A,
                                                    const unsigned short* __restrict__ Wp,
                                                    unsigned short* __restrict__ out, int nrows) {
  __shared__ __align__(16) unsigned short Wl[16384];
  gemm_body(Wl, A, Wp, out, nrows, blockIdx.x);
}

// ---------------- agg: one wave per node, tail-free (8-padded CSR) ----------------
// r11-verified structure (half-wave edge parity, ushort4 gathers, hoisted epilogue).

template <int RES, int OUTBF>
__global__ __launch_bounds__(256) void agg_kernel(const unsigned short* __restrict__ h,
                                                  const int* __restrict__ rowptr,
                                                  const int2* __restrict__ csr,
                                                  const float* __restrict__ dinv,
                                                  const float* __restrict__ bias,
                                                  const float* __restrict__ res,
                                                  void* __restrict__ outv, int n) {
  int node = blockIdx.x * 4 + (threadIdx.x >> 6);
  if (node >= n) return;
  const int lane = threadIdx.x & 63;
  const int p = lane >> 5;          // edge parity this half-wave handles
  const int c4 = (lane & 31) << 2;  // 4 columns per lane
  int j = rowptr[node];
  const int end = rowptr[node + 1];

  // hoisted epilogue inputs (independent of the gather loop)
  const float di = dinv[node];
  const ushort4 hs = *(const ushort4*)(h + (size_t)node * HH + c4);
  const float4 b = *(const float4*)(bias + c4);
  float4 rr = make_float4(0.f, 0.f, 0.f, 0.f);
  if (RES) rr = *(const float4*)(res + (size_t)node * HH + c4);

  float a0 = 0.f, a1 = 0.f, a2 = 0.f, a3 = 0.f;
  // 8 edges per iteration (4 per half-wave), 4 ushort4 gathers in flight/lane
  for (; j < end; j += 8) {
    int2 e[4];
    ushort4 r[4];
#pragma unroll
    for (int q = 0; q < 4; ++q) e[q] = csr[j + 2 * q + p];
#pragma unroll
    for (int q = 0; q < 4; ++q) r[q] = *(const ushort4*)(h + (size_t)e[q].x * HH + c4);
#pragma unroll
    for (int q = 0; q < 4; ++q) {
      float nv = __int_as_float(e[q].y);
      a0 = fmaf(b2f(r[q].x), nv, a0); a1 = fmaf(b2f(r[q].y), nv, a1);
      a2 = fmaf(b2f(r[q].z), nv, a2); a3 = fmaf(b2f(r[q].w), nv, a3);
    }
  }

  // combine the two edge-parity halves (lane L <-> lane L^32, same columns)
  a0 += __shfl_xor(a0, 32);
  a1 += __shfl_xor(a1, 32);
  a2 += __shfl_xor(a2, 32);
  a3 += __shfl_xor(a3, 32);

  if (p == 0) {  // lanes 0-31: epilogue + store (16B accesses)
    const float d2 = di * di;
    float o0 = a0 + b2f(hs.x) * d2 + b.x + rr.x;
    float o1 = a1 + b2f(hs.y) * d2 + b.y + rr.y;
    float o2 = a2 + b2f(hs.z) * d2 + b.z + rr.z;
    float o3 = a3 + b2f(hs.w) * d2 + b.w + rr.w;
    o0 = lrelu(o0); o1 = lrelu(o1); o2 = lrelu(o2); o3 = lrelu(o3);
    if (OUTBF) {
      ushort4 o;
      o.x = f2b(o0); o.y = f2b(o1); o.z = f2b(o2); o.w = f2b(o3);
      *(ushort4*)((unsigned short*)outv + (size_t)node * HH + c4) = o;
    } else {
      *(float4*)((float*)outv + (size_t)node * HH + c4) = make_float4(o0, o1, o2, o3);
    }
  }
}

// ---------------- fusedMLP: 4-GEMM chain, double-buffered W, 4 barriers --------
// r12-verified: Wl[2] ping-pong; W3/W4 DMAs covered by full MFMA stages; one
// tile T per wave; f2 residual in regs; gen parked in T; biases in regs.

__global__ __launch_bounds__(256, 1) void fusedMLP(const unsigned short* __restrict__ f2bf,
                                                   const unsigned short* __restrict__ Wm1p,
                                                   const unsigned short* __restrict__ Wm2p,
                                                   const unsigned short* __restrict__ Wp1p,
                                                   const unsigned short* __restrict__ Wp2p,
                                                   const float* __restrict__ bm1,
                                                   const float* __restrict__ bm2,
                                                   const float* __restrict__ bp1,
                                                   const float* __restrict__ bp2,
                                                   const float* __restrict__ gen,
                                                   float* __restrict__ out, int n) {
  __shared__ __align__(16) unsigned short Wl[2][16384];   // 64KB weight ping-pong
  __shared__ __align__(16) unsigned short Tl[4][16 * HH]; // 16KB: one 4KB tile/wave
  const int tid = threadIdx.x;
  const int lane = tid & 63, wave = tid >> 6;
  const int row0 = blockIdx.x * 64 + wave * 16;
  const int m = lane & 15, quad = lane >> 4;
  unsigned short* T = Tl[wave];

  // --- issue W1 -> Wl[0] and W2 -> Wl[1] DMAs first (async) ---
#pragma unroll
  for (int i = 0; i < 8; ++i) {
    gll16((const uint4*)Wm1p + i * 256 + tid, (uint4*)Wl[0] + i * 256 + wave * 64);
    gll16((const uint4*)Wm2p + i * 256 + tid, (uint4*)Wl[1] + i * 256 + wave * 64);
  }

  // --- f2 tile -> T (swizzled), 4 x 16B per lane ---
#pragma unroll
  for (int i = 0; i < 4; ++i) {
    int idx = i * 64 + lane;            // 16B-chunk id 0..255
    int r = idx >> 4, k = (idx & 15) << 3;
    int gr = row0 + r;
    ushort8v v = {0, 0, 0, 0, 0, 0, 0, 0};
    if (gr < n) v = *(const ushort8v*)(f2bf + (size_t)gr * HH + k);
    *(ushort8v*)&T[lofs(r, k)] = v;
  }

  // --- gen -> bf16 regs in staging-chunk layout (parked into T at stage 2) ---
  ushort4 genb[8];
#pragma unroll
  for (int i = 0; i < 8; ++i) {
    int idx = i * 64 + lane;            // float4-chunk id 0..511
    int r = idx >> 5, c4 = (idx & 31) << 2;
    int gr = row0 + r;
    float4 v = make_float4(0.f, 0.f, 0.f, 0.f);
    if (gr < n) v = *(const float4*)(gen + (size_t)gr * HH + c4);
    genb[i].x = f2b(v.x); genb[i].y = f2b(v.y); genb[i].z = f2b(v.z); genb[i].w = f2b(v.w);
  }

  // --- all 4 bias sets -> registers (hidden under DMAs) ---
  float bvAll[4][8];
#pragma unroll
  for (int cc = 0; cc < 8; ++cc) {
    int col = cc * 16 + m;
    bvAll[0][cc] = bm1[col];
    bvAll[1][cc] = bm2[col];
    bvAll[2][cc] = bp1[col];
    bvAll[3][cc] = bp2[col];
  }

  __syncthreads();  // B1: vmcnt drain -> W1, W2, T visible

  bf16x8 af[4];
  f32x4 acc[8];

  // ---- stage 1: m = leaky(f2@Wm1+bm1) ----
  lds_afrags16(T, m, quad, af);
  // capture f2 residual (C-fragment slots) into 16 regs before T is overwritten
  unsigned f2res[8][2];
#pragma unroll
  for (int cc = 0; cc < 8; ++cc) {
    int col = cc * 16 + m;
#pragma unroll
    for (int gp = 0; gp < 2; ++gp) {
      int lr = quad * 4 + gp * 2;
      f2res[cc][gp] = (unsigned)T[lofs(lr, col)] | ((unsigned)T[lofs(lr + 1, col)] << 16);
    }
  }
  mfma_ldsW(af, Wl[0], lane, acc);
  WAVE_SYNC();  // all T reads drained before overwrite
#pragma unroll
  for (int cc = 0; cc < 8; ++cc) {
    int col = cc * 16 + m;
#pragma unroll
    for (int g = 0; g < 4; ++g)
      T[lofs(quad * 4 + g, col)] = f2b(lrelu(acc[cc][g] + bvAll[0][cc]));
  }
  __syncthreads();  // B2: all waves done reading W1 (Wl[0] free)

  // issue W3 -> Wl[0] (covered by all of stage 2)
#pragma unroll
  for (int i = 0; i < 8; ++i)
    gll16((const uint4*)Wp1p + i * 256 + tid, (uint4*)Wl[0] + i * 256 + wave * 64);

  // ---- stage 2: h3 = leaky(m@Wm2+bm2+f2res); p = 0.5*(h3+gen) ----
  lds_afrags16(T, m, quad, af);  // consume m into regs
  WAVE_SYNC();                   // m reads done before gen park overwrites T
  // park gen into T (staging layout)
#pragma unroll
  for (int i = 0; i < 8; ++i) {
    int idx = i * 64 + lane;
    int r = idx >> 5, c4 = (idx & 31) << 2;
    *(ushort4*)&T[lofs(r, c4)] = genb[i];
  }
  mfma_ldsW(af, Wl[1], lane, acc);  // W2 resident since B1
  WAVE_SYNC();                      // gen park visible for C-slot reads
#pragma unroll
  for (int cc = 0; cc < 8; ++cc) {
    int col = cc * 16 + m;
#pragma unroll
    for (int g = 0; g < 4; ++g) {
      int lr = quad * 4 + g;
      unsigned fr = f2res[cc][g >> 1];
      float f2v = b2f((unsigned short)((g & 1) ? (fr >> 16) : (fr & 0xffffu)));
      float v = lrelu(acc[cc][g] + bvAll[1][cc] + f2v);
      float gv = b2f(T[lofs(lr, col)]);     // gen parked (same-lane slot)
      T[lofs(lr, col)] = f2b(0.5f * (v + gv));
    }
  }
  __syncthreads();  // B3: all waves done reading W2 (Wl[1] free); W3 visible

  // issue W4 -> Wl[1] (covered by all of stage 3)
#pragma unroll
  for (int i = 0; i < 8; ++i)
    gll16((const uint4*)Wp2p + i * 256 + tid, (uint4*)Wl[1] + i * 256 + wave * 64);

  // ---- stage 3: q = leaky(p@Wp1+bp1) ----
  lds_afrags16(T, m, quad, af);
  mfma_ldsW(af, Wl[0], lane, acc);
  WAVE_SYNC();  // p reads drained before overwrite
#pragma unroll
  for (int cc = 0; cc < 8; ++cc) {
    int col = cc * 16 + m;
#pragma unroll
    for (int g = 0; g < 4; ++g)
      T[lofs(quad * 4 + g, col)] = f2b(lrelu(acc[cc][g] + bvAll[2][cc]));
  }
  __syncthreads();  // B4: W4 visible; T(q) visible

  // ---- stage 4: out = leaky(q@Wp2+bp2) ----
  lds_afrags16(T, m, quad, af);
  mfma_ldsW(af, Wl[1], lane, acc);
#pragma unroll
  for (int cc = 0; cc < 8; ++cc) {
    int col = cc * 16 + m;
#pragma unroll
    for (int g = 0; g < 4; ++g) {
      int row = row0 + quad * 4 + g;
      if (row < n) out[(size_t)row * HH + col] = lrelu(acc[cc][g] + bvAll[3][cc]);
    }
  }
}

// ---------------- launcher (9 dispatches, was 13) ----------------

extern "C" void kernel_launch(void* const* d_in, const int* in_sizes, int n_in,
                              void* d_out, int out_size, void* d_ws, size_t ws_size,
                              hipStream_t stream) {
  const float* x   = (const float*)d_in[0];
  const int* ei    = (const int*)d_in[1];
  const float* gen = (const float*)d_in[2];
  const float* Wc1 = (const float*)d_in[3];
  const float* bc1 = (const float*)d_in[4];
  const float* Wc2 = (const float*)d_in[5];
  const float* bc2 = (const float*)d_in[6];
  const float* Wm1 = (const float*)d_in[7];
  const float* bm1 = (const float*)d_in[8];
  const float* Wm2 = (const float*)d_in[9];
  const float* bm2 = (const float*)d_in[10];
  const float* Wp1 = (const float*)d_in[11];
  const float* bp1 = (const float*)d_in[12];
  const float* Wp2 = (const float*)d_in[13];
  const float* bp2 = (const float*)d_in[14];

  const int N = in_sizes[0] / HH;
  const int E = in_sizes[1] / 2;
  const int* src = ei;
  const int* dst = ei + E;

  const size_t Epad = (size_t)E + 8 * (size_t)N;  // worst-case padded edge count

  char* ws = (char*)d_ws;
  size_t off = 0;
  auto alloc = [&](size_t bytes) { void* p = ws + off; off += (bytes + 255) & ~(size_t)255; return p; };
  float* dinv            = (float*)alloc((size_t)N * 4);
  int*   rowptr          = (int*)  alloc((size_t)(N + 1) * 4);
  int*   bsum            = (int*)  alloc((size_t)64 * 4);
  int*   rank            = (int*)  alloc((size_t)E * 4);
  int*   cnt             = (int*)  alloc((size_t)N * 4);   // adjacent to csr:
  int2*  csr             = (int2*) alloc(Epad * 8);        // single memset spans both
  unsigned short* h_bf   = (unsigned short*)alloc((size_t)N * HH * 2);
  unsigned short* t2_bf  = (unsigned short*)alloc((size_t)N * HH * 2);
  unsigned short* f2_bf  = (unsigned short*)alloc((size_t)N * HH * 2);
  float* f1_f32          = (float*)alloc((size_t)N * HH * 4);
  unsigned short* packed = (unsigned short*)alloc((size_t)6 * 16384 * 2);
  float* fOut = (float*)d_out;

  const int cblocks = (N + 63) / 64;      // 4 waves x 16 rows per 256-thr block
  const int eblocks = (E + 255) / 256;
  const int ablocks = (N + 3) / 4;
  const int sblocks = (N + 1023) / 1024;  // <= 64 for N <= 65536

  // D1: single memset spanning cnt + csr (adjacent in ws)
  size_t zbytes = (size_t)((char*)csr + Epad * 8 - (char*)cnt);
  hipMemsetAsync(cnt, 0, zbytes, stream);

  // D2: pack || count (independent stages co-scheduled)
  k_pack_count<<<384 + eblocks, 256, 0, stream>>>(Wc1, Wc2, Wm1, Wm2, Wp1, Wp2, packed,
                                                  dst, cnt, rank, E);

  // D3/D4: scans (scan2 folded into scan3)
  scan1_kernel<<<sblocks, 1024, 0, stream>>>(cnt, rowptr, bsum, dinv, N);
  scan3_kernel<<<sblocks, 1024, 0, stream>>>(rowptr, bsum, N, sblocks);

  // D5: gemm1 || fill (independent given D2-D4 outputs)
  k_gemm_fill<<<cblocks + eblocks, 256, 0, stream>>>(x, packed + 0 * 16384, h_bf, N,
                                                     cblocks, src, dst, rowptr, rank,
                                                     dinv, csr, E);

  // D6: agg1: f1 = leaky(agg(h_bf)+self+bc1)  [fp32]
  agg_kernel<0, 0><<<ablocks, 256, 0, stream>>>(h_bf, rowptr, csr, dinv, bc1, nullptr, f1_f32, N);
  // D7: conv2: t2 = bf16(f1 @ Wc2)
  gemm_conv<<<cblocks, 256, 0, stream>>>(f1_f32, packed + 1 * 16384, t2_bf, N);
  // D8: agg2: f2 = leaky(agg(t2)+self+bc2+f1)  [bf16]
  agg_kernel<1, 1><<<ablocks, 256, 0, stream>>>(t2_bf, rowptr, csr, dinv, bc2, f1_f32, f2_bf, N);
  // D9: fusedMLP: MLP + interp + proj -> d_out
  fusedMLP<<<cblocks, 256, 0, stream>>>(f2_bf,
                                        packed + 2 * 16384, packed + 3 * 16384,
                                        packed + 4 * 16384, packed + 5 * 16384,
                                        bm1, bm2, bp1, bp2, gen, fOut, N);
}